// Round 1
// baseline (234.176 us; speedup 1.0000x reference)
//
#include <hip/hip_runtime.h>
#include <hip/hip_bf16.h>
#include <cstdint>
#include <cstddef>

#define D_MODEL 1024
#define NHEADS  16
#define DEPTH   64
#define BATCH   2
#define SEQ     2048
#define M_TOT   (BATCH*SEQ)   // 4096

typedef __attribute__((ext_vector_type(8))) __bf16 bf16x8;
typedef __attribute__((ext_vector_type(4))) float  f32x4;

__device__ inline unsigned short f2bf(float f){
  unsigned u = __float_as_uint(f);
  u += 0x7FFFu + ((u>>16)&1u);
  return (unsigned short)(u>>16);
}

#define AS1(p) ((__attribute__((address_space(1))) void*)(p))
#define AS3(p) ((__attribute__((address_space(3))) void*)(p))

// ---------------- fp32 -> bf16 elementwise (vectorized) ----------------
__global__ void cvt_bf16(const float* __restrict__ in, unsigned short* __restrict__ out, int n4){
  int i = blockIdx.x*blockDim.x + threadIdx.x;
  if (i >= n4) return;
  float4 v = ((const float4*)in)[i];
  ushort4 o;
  o.x = f2bf(v.x); o.y = f2bf(v.y); o.z = f2bf(v.z); o.w = f2bf(v.w);
  ((ushort4*)out)[i] = o;
}

// ---------------- W [K,N] fp32 -> Wt [N,K] bf16 (LDS tiled transpose) ----------------
__global__ void tcvt(const float* __restrict__ W, unsigned short* __restrict__ Wt){
  __shared__ float t[32][33];
  int bx = blockIdx.x*32, by = blockIdx.y*32;
  for (int j = threadIdx.y; j < 32; j += 8)
    t[j][threadIdx.x] = W[(size_t)(by+j)*D_MODEL + bx + threadIdx.x];
  __syncthreads();
  for (int j = threadIdx.y; j < 32; j += 8)
    Wt[(size_t)(bx+j)*D_MODEL + by + threadIdx.x] = f2bf(t[threadIdx.x][j]);
}

// ---------------- GEMM: C[M,N] = A[M,K] @ Bt[N,K]^T + bias ----------------
// MODE 0: write bf16 [B,H,S,D]   (Q,K projections)
// MODE 1: write bf16 [B,H,D,S]   (V projection, transposed per head)
// MODE 2: write fp32 [M,N]       (output projection -> d_out)
#define BM 128
#define BN 64
#define BK 32
#define GK 1024

template<int MODE>
__global__ __launch_bounds__(256,2) void gemm_bt(
    const unsigned short* __restrict__ A,
    const unsigned short* __restrict__ Bt,
    const float* __restrict__ bias,
    void* __restrict__ Cout)
{
  __shared__ __align__(16) short As[BM*BK];  // 8 KB, row stride 64 B
  __shared__ __align__(16) short Bs[BN*BK];  // 4 KB
  const int tid = threadIdx.x, lane = tid & 63, wave = tid >> 6;
  const int m0 = blockIdx.x*BM, n0 = blockIdx.y*BN;
  const int wm = wave >> 1, wn = wave & 1;

  f32x4 acc[4][2];
  #pragma unroll
  for (int i=0;i<4;i++)
    #pragma unroll
    for (int j=0;j<2;j++)
      acc[i][j] = (f32x4){0.f,0.f,0.f,0.f};

  const char* Abase = (const char*)A + (size_t)m0*GK*2;
  const char* Bbase = (const char*)Bt + (size_t)n0*GK*2;
  const int crow = lane >> 2;        // row within 16-row chunk
  const int ccb  = (lane & 3) * 16;  // byte within 64-B row

  for (int k0 = 0; k0 < GK; k0 += BK){
    #pragma unroll
    for (int i=0;i<2;i++){
      int c = wave*2 + i;            // A chunks 0..7
      __builtin_amdgcn_global_load_lds(
        AS1(Abase + (size_t)(c*16 + crow)*(GK*2) + k0*2 + ccb),
        AS3((char*)As + c*1024), 16, 0, 0);
    }
    {
      int c = wave;                  // B chunks 0..3
      __builtin_amdgcn_global_load_lds(
        AS1(Bbase + (size_t)(c*16 + crow)*(GK*2) + k0*2 + ccb),
        AS3((char*)Bs + c*1024), 16, 0, 0);
    }
    __syncthreads();

    bf16x8 af[4], bfv[2];
    #pragma unroll
    for (int i=0;i<4;i++)
      af[i] = *(const bf16x8*)((const char*)As + (wm*64 + i*16 + (lane&15))*64 + (lane>>4)*16);
    #pragma unroll
    for (int j=0;j<2;j++)
      bfv[j] = *(const bf16x8*)((const char*)Bs + (wn*32 + j*16 + (lane&15))*64 + (lane>>4)*16);
    #pragma unroll
    for (int i=0;i<4;i++)
      #pragma unroll
      for (int j=0;j<2;j++)
        acc[i][j] = __builtin_amdgcn_mfma_f32_16x16x32_bf16(af[i], bfv[j], acc[i][j], 0,0,0);
    __syncthreads();
  }

  #pragma unroll
  for (int i=0;i<4;i++)
    #pragma unroll
    for (int j=0;j<2;j++)
      #pragma unroll
      for (int r=0;r<4;r++){
        int gr = m0 + wm*64 + i*16 + (lane>>4)*4 + r;
        int gc = n0 + wn*32 + j*16 + (lane&15);
        float v = acc[i][j][r] + bias[gc];
        if (MODE == 0){
          int b = gr>>11, s = gr&2047, h = gc>>6, d = gc&63;
          ((unsigned short*)Cout)[(((size_t)(b*NHEADS+h))*SEQ + s)*DEPTH + d] = f2bf(v);
        } else if (MODE == 1){
          int b = gr>>11, s = gr&2047, h = gc>>6, d = gc&63;
          ((unsigned short*)Cout)[(((size_t)(b*NHEADS+h))*DEPTH + d)*SEQ + s] = f2bf(v);
        } else {
          ((float*)Cout)[(size_t)gr*D_MODEL + gc] = v;
        }
      }
}

// ---------------- causal flash attention ----------------
// grid (S/64, B*H), 256 threads (4 waves x 16 Q-rows). KV tile = 64.
// Q,K: [BH][S][64] bf16. Vt: [BH][64][S] bf16. Out: [B][S][H*64] bf16.
__global__ __launch_bounds__(256) void attn_fwd(
  const unsigned short* __restrict__ Qh,
  const unsigned short* __restrict__ Kh,
  const unsigned short* __restrict__ Vt,
  unsigned short* __restrict__ AO)
{
  __shared__ __align__(16) short Ks[64*64];     // [kv][d] rows 128 B, swizzled
  __shared__ __align__(16) short Vs[64*64];     // [d][kv] rows 128 B, swizzled
  __shared__ __align__(16) short Ps[4][16*64];  // per-wave P [16][64], swizzled

  const int tid = threadIdx.x, lane = tid & 63, w = tid >> 6;
  const int qt = blockIdx.x, bh = blockIdx.y;
  const int q0 = qt*64;
  const size_t hb = (size_t)bh*SEQ*DEPTH;   // element offset (same for QK and Vt)

  bf16x8 aq[2];
  {
    const unsigned short* qp = Qh + hb + (size_t)(q0 + w*16 + (lane&15))*DEPTH + (lane>>4)*8;
    aq[0] = *(const bf16x8*)qp;
    aq[1] = *(const bf16x8*)(qp + 32);
  }

  f32x4 oacc[4];
  #pragma unroll
  for (int i=0;i<4;i++) oacc[i] = (f32x4){0.f,0.f,0.f,0.f};
  float mrow[4] = {-1e30f,-1e30f,-1e30f,-1e30f};
  float srow[4] = {0.f,0.f,0.f,0.f};

  const char* Kb = (const char*)(Kh + hb);
  const char* Vb = (const char*)(Vt + hb);

  for (int t = 0; t <= qt; ++t){
    const int kv0 = t*64;
    // stage K (8 KB) and Vt (8 KB): 8 chunks each, 2 per wave.
    // LDS dest is linear; global source column pre-swizzled (involution byte^((row&7)<<4))
    #pragma unroll
    for (int i=0;i<2;i++){
      int c = w*2 + i;
      int x = c*1024 + lane*16;            // linear LDS byte
      int row = x >> 7;                    // tile row (128-B rows)
      int cb = (x & 127) ^ ((row&7)<<4);   // source column byte
      __builtin_amdgcn_global_load_lds(
        AS1(Kb + (size_t)(kv0+row)*128 + cb),
        AS3((char*)Ks + c*1024), 16, 0, 0);
      __builtin_amdgcn_global_load_lds(
        AS1(Vb + ((size_t)row*SEQ + kv0)*2 + cb),
        AS3((char*)Vs + c*1024), 16, 0, 0);
    }
    __syncthreads();

    // ---- QK^T : logits 16x64 per wave ----
    f32x4 lacc[4];
    #pragma unroll
    for (int i=0;i<4;i++) lacc[i] = (f32x4){0.f,0.f,0.f,0.f};
    #pragma unroll
    for (int ks=0; ks<2; ++ks){
      #pragma unroll
      for (int nb=0; nb<4; ++nb){
        int bo = (nb*16 + (lane&15))*128 + ks*64 + (lane>>4)*16;
        bo ^= ((bo>>7)&7) << 4;
        bf16x8 bk = *(const bf16x8*)((const char*)Ks + bo);
        lacc[nb] = __builtin_amdgcn_mfma_f32_16x16x32_bf16(aq[ks], bk, lacc[nb], 0,0,0);
      }
    }

    // ---- scale + causal mask + online softmax ----
    const bool diag = (t == qt);
    float lg[4][4];
    #pragma unroll
    for (int nb=0;nb<4;nb++)
      #pragma unroll
      for (int r=0;r<4;r++){
        float v = lacc[nb][r]*0.125f;
        if (diag && (nb*16 + (lane&15)) > (w*16 + (lane>>4)*4 + r)) v -= 1e9f;
        lg[nb][r] = v;
      }
    float pm[4];
    #pragma unroll
    for (int r=0;r<4;r++)
      pm[r] = fmaxf(fmaxf(lg[0][r],lg[1][r]), fmaxf(lg[2][r],lg[3][r]));
    #pragma unroll
    for (int off=1; off<16; off<<=1)
      #pragma unroll
      for (int r=0;r<4;r++)
        pm[r] = fmaxf(pm[r], __shfl_xor(pm[r], off, 64));
    float fac[4];
    #pragma unroll
    for (int r=0;r<4;r++){
      float mn = fmaxf(mrow[r], pm[r]);
      fac[r] = __expf(mrow[r]-mn);
      mrow[r] = mn;
    }
    float ps[4] = {0.f,0.f,0.f,0.f};
    #pragma unroll
    for (int nb=0;nb<4;nb++)
      #pragma unroll
      for (int r=0;r<4;r++){
        float p = __expf(lg[nb][r]-mrow[r]);
        lg[nb][r] = p;
        ps[r] += p;
      }
    #pragma unroll
    for (int off=1; off<16; off<<=1)
      #pragma unroll
      for (int r=0;r<4;r++)
        ps[r] += __shfl_xor(ps[r], off, 64);
    #pragma unroll
    for (int r=0;r<4;r++) srow[r] = srow[r]*fac[r] + ps[r];

    // ---- P -> LDS (bf16, swizzled) ----
    #pragma unroll
    for (int nb=0;nb<4;nb++)
      #pragma unroll
      for (int r=0;r<4;r++){
        int row = (lane>>4)*4 + r, col = nb*16 + (lane&15);
        Ps[w][row*64 + (col ^ ((row&7)<<3))] = (short)f2bf(lg[nb][r]);
      }

    // ---- rescale O ----
    #pragma unroll
    for (int nb=0;nb<4;nb++){
      oacc[nb][0]*=fac[0]; oacc[nb][1]*=fac[1];
      oacc[nb][2]*=fac[2]; oacc[nb][3]*=fac[3];
    }

    // ---- PV ----
    #pragma unroll
    for (int ks=0;ks<2;ks++){
      int pb = (lane&15)*128 + ks*64 + (lane>>4)*16;
      pb ^= ((pb>>7)&7) << 4;
      bf16x8 pa = *(const bf16x8*)((const char*)(&Ps[w][0]) + pb);
      #pragma unroll
      for (int nb=0;nb<4;nb++){
        int vb2 = (nb*16 + (lane&15))*128 + ks*64 + (lane>>4)*16;
        vb2 ^= ((vb2>>7)&7) << 4;
        bf16x8 bv = *(const bf16x8*)((const char*)Vs + vb2);
        oacc[nb] = __builtin_amdgcn_mfma_f32_16x16x32_bf16(pa, bv, oacc[nb], 0,0,0);
      }
    }
    __syncthreads();
  }

  const int b = bh >> 4, h = bh & 15;
  #pragma unroll
  for (int nb=0;nb<4;nb++)
    #pragma unroll
    for (int r=0;r<4;r++){
      int row = q0 + w*16 + (lane>>4)*4 + r;
      int col = h*DEPTH + nb*16 + (lane&15);
      AO[((size_t)b*SEQ + row)*D_MODEL + col] = f2bf(oacc[nb][r]/srow[r]);
    }
}

// ---------------- launcher ----------------
extern "C" void kernel_launch(void* const* d_in, const int* in_sizes, int n_in,
                              void* d_out, int out_size, void* d_ws, size_t ws_size,
                              hipStream_t stream) {
  const float* query  = (const float*)d_in[0];
  const float* key_in = (const float*)d_in[1];
  const float* value  = (const float*)d_in[2];
  // d_in[3] = mask (unused; causal handled analytically)
  const float* wq = (const float*)d_in[4];
  const float* bq = (const float*)d_in[5];
  const float* wk = (const float*)d_in[6];
  const float* bk = (const float*)d_in[7];
  const float* wv = (const float*)d_in[8];
  const float* bv = (const float*)d_in[9];
  const float* wo = (const float*)d_in[10];
  const float* bo = (const float*)d_in[11];

  char* ws = (char*)d_ws;
  const size_t MB = 1u<<20;
  unsigned short* Xq  = (unsigned short*)(ws + 0*MB);   // [4096,1024] bf16
  unsigned short* Xk  = (unsigned short*)(ws + 8*MB);
  unsigned short* Xv  = (unsigned short*)(ws + 16*MB);
  unsigned short* Wtq = (unsigned short*)(ws + 24*MB);  // [N,K] bf16
  unsigned short* Wtk = (unsigned short*)(ws + 26*MB);
  unsigned short* Wtv = (unsigned short*)(ws + 28*MB);
  unsigned short* Wto = (unsigned short*)(ws + 30*MB);
  unsigned short* Qh  = (unsigned short*)(ws + 32*MB);  // [B,H,S,D] bf16
  unsigned short* Kh  = (unsigned short*)(ws + 40*MB);  // [B,H,S,D] bf16
  unsigned short* Vth = (unsigned short*)(ws + 48*MB);  // [B,H,D,S] bf16
  unsigned short* AO  = (unsigned short*)(ws + 56*MB);  // [B,S,1024] bf16

  const int n4 = (M_TOT*D_MODEL)/4;  // 1048576
  cvt_bf16<<<n4/256, 256, 0, stream>>>(query,  Xq, n4);
  cvt_bf16<<<n4/256, 256, 0, stream>>>(key_in, Xk, n4);
  cvt_bf16<<<n4/256, 256, 0, stream>>>(value,  Xv, n4);

  dim3 tg(32,32), tb(32,8);
  tcvt<<<tg, tb, 0, stream>>>(wq, Wtq);
  tcvt<<<tg, tb, 0, stream>>>(wk, Wtk);
  tcvt<<<tg, tb, 0, stream>>>(wv, Wtv);
  tcvt<<<tg, tb, 0, stream>>>(wo, Wto);

  dim3 gg(M_TOT/BM, D_MODEL/BN);   // (32,16)
  gemm_bt<0><<<gg, 256, 0, stream>>>(Xq, Wtq, bq, Qh);
  gemm_bt<0><<<gg, 256, 0, stream>>>(Xk, Wtk, bk, Kh);
  gemm_bt<1><<<gg, 256, 0, stream>>>(Xv, Wtv, bv, Vth);

  dim3 ag(SEQ/64, BATCH*NHEADS);   // (32,32)
  attn_fwd<<<ag, 256, 0, stream>>>(Qh, Kh, Vth, AO);

  gemm_bt<2><<<gg, 256, 0, stream>>>(AO, Wto, bo, d_out);
}